// Round 1
// baseline (142.114 us; speedup 1.0000x reference)
//
#include <hip/hip_runtime.h>
#include <math.h>

// FilterBankConstructorND: K spheres of dim D+2=5, D=3, M=4 tetra rotations.
// Per sphere k:
//   p = normalize(spheres[k,:3] / (spheres[k,4]+eps)); q = normalize(ones_vec)
//   u = p+q;  a = 2/||u||^2;  w_j = q_j - a*(q.u)*u_j;  b2 = 2/||q||^2
//   R0[i][j] = delta_ij - a*u_i*u_j - b2*q_i*w_j          (R0 @ p = q)
//   r = R0 @ s_top
//   for m: f = R0^T @ (T_m @ r);  fb[m] = (f0,f1,f2,s3,s4)
// Output: concat( R0 (K*9 floats), filter_banks (K*M*5 floats) )

__global__ __launch_bounds__(256) void fbank_kernel(
    const float* __restrict__ spheres,
    const float* __restrict__ ones_vec,
    const float* __restrict__ tetra,
    float* __restrict__ out,
    int K)
{
    __shared__ float sT[36];
    __shared__ __align__(16) float rot_s[256 * 9];    //  9 KB, stride 9 (odd -> conflict-free)
    __shared__ __align__(16) float fb_s[256 * 21];    // 21 KB, stride 21 (odd -> conflict-free)

    const int tid = threadIdx.x;
    if (tid < 36) sT[tid] = tetra[tid];
    __syncthreads();

    int k = blockIdx.x * 256 + tid;
    int ks = (k < K) ? k : (K - 1);  // clamp: tail threads compute a duplicate, never flushed

    const float* sp = spheres + (size_t)ks * 5;
    const float s0 = sp[0], s1 = sp[1], s2 = sp[2], s3 = sp[3], s4 = sp[4];

    // unembed + normalize center
    const float inv = 1.0f / (s4 + 1e-12f);
    const float c0 = s0 * inv, c1 = s1 * inv, c2 = s2 * inv;
    const float cn = sqrtf(c0 * c0 + c1 * c1 + c2 * c2);
    const float p0 = c0 / cn, p1 = c1 / cn, p2 = c2 / cn;

    // normalized ones vector (uniform; L1/scalar-cached)
    float o0 = ones_vec[0], o1 = ones_vec[1], o2 = ones_vec[2];
    const float on = sqrtf(o0 * o0 + o1 * o1 + o2 * o2);
    o0 /= on; o1 /= on; o2 /= on;

    // two Householder reflections composed: R0 = H_q * H_{p+q}
    const float u0 = p0 + o0, u1 = p1 + o1, u2 = p2 + o2;
    const float a  = 2.0f / (u0 * u0 + u1 * u1 + u2 * u2);
    const float tq = o0 * u0 + o1 * u1 + o2 * u2;
    const float w0 = o0 - a * tq * u0, w1 = o1 - a * tq * u1, w2 = o2 - a * tq * u2;
    const float b2 = 2.0f / (o0 * o0 + o1 * o1 + o2 * o2);

    const float uu[3] = {u0, u1, u2}, oo[3] = {o0, o1, o2}, ww[3] = {w0, w1, w2};
    float R[3][3];
#pragma unroll
    for (int i = 0; i < 3; ++i)
#pragma unroll
        for (int j = 0; j < 3; ++j)
            R[i][j] = ((i == j) ? 1.0f : 0.0f) - a * uu[i] * uu[j] - b2 * oo[i] * ww[j];

    // r = R0 @ s_top
    const float r0 = R[0][0] * s0 + R[0][1] * s1 + R[0][2] * s2;
    const float r1 = R[1][0] * s0 + R[1][1] * s1 + R[1][2] * s2;
    const float r2 = R[2][0] * s0 + R[2][1] * s1 + R[2][2] * s2;

    float fb[20];
#pragma unroll
    for (int m = 0; m < 4; ++m) {
        const float* T = sT + m * 9;
        const float g0 = T[0] * r0 + T[1] * r1 + T[2] * r2;
        const float g1 = T[3] * r0 + T[4] * r1 + T[5] * r2;
        const float g2 = T[6] * r0 + T[7] * r1 + T[8] * r2;
        // f = R0^T @ g
        fb[m * 5 + 0] = R[0][0] * g0 + R[1][0] * g1 + R[2][0] * g2;
        fb[m * 5 + 1] = R[0][1] * g0 + R[1][1] * g1 + R[2][1] * g2;
        fb[m * 5 + 2] = R[0][2] * g0 + R[1][2] * g1 + R[2][2] * g2;
        fb[m * 5 + 3] = s3;
        fb[m * 5 + 4] = s4;
    }

    // stage into LDS
#pragma unroll
    for (int i = 0; i < 3; ++i)
#pragma unroll
        for (int j = 0; j < 3; ++j)
            rot_s[tid * 9 + i * 3 + j] = R[i][j];
#pragma unroll
    for (int i = 0; i < 20; ++i)
        fb_s[tid * 21 + i] = fb[i];
    __syncthreads();

    // flush rotations: 256*9 = 2304 floats = 576 float4, contiguous & coalesced
    {
        float* rot_out = out + (size_t)blockIdx.x * 2304;
        const long long lim = (long long)K * 9 - (long long)blockIdx.x * 2304;
        for (int i = tid; i < 576; i += 256) {
            if ((long long)i * 4 + 3 < lim) {
                float4 v = *(const float4*)&rot_s[i * 4];
                *(float4*)(rot_out + (size_t)i * 4) = v;
            }
        }
    }
    // flush filter banks: 256*20 = 5120 floats = 1280 float4
    {
        float* fb_out = out + (size_t)K * 9 + (size_t)blockIdx.x * 5120;
        const long long lim = (long long)K * 20 - (long long)blockIdx.x * 5120;
        for (int i = tid; i < 1280; i += 256) {
            const int f = i * 4;
            if ((long long)f + 3 < lim) {
                float4 v;
                v.x = fb_s[((f + 0) / 20) * 21 + (f + 0) % 20];
                v.y = fb_s[((f + 1) / 20) * 21 + (f + 1) % 20];
                v.z = fb_s[((f + 2) / 20) * 21 + (f + 2) % 20];
                v.w = fb_s[((f + 3) / 20) * 21 + (f + 3) % 20];
                *(float4*)(fb_out + f) = v;
            }
        }
    }
}

extern "C" void kernel_launch(void* const* d_in, const int* in_sizes, int n_in,
                              void* d_out, int out_size, void* d_ws, size_t ws_size,
                              hipStream_t stream) {
    const float* spheres  = (const float*)d_in[0];   // (K, 5)
    const float* ones_vec = (const float*)d_in[1];   // (3,)
    const float* tetra    = (const float*)d_in[2];   // (4, 3, 3)
    float* out = (float*)d_out;                      // K*9 rot, then K*4*5 fb
    const int K = in_sizes[0] / 5;
    const int grid = (K + 255) / 256;
    fbank_kernel<<<grid, 256, 0, stream>>>(spheres, ones_vec, tetra, out, K);
}